// Round 1
// baseline (528.313 us; speedup 1.0000x reference)
//
#include <hip/hip_runtime.h>

#define GRID_RES 64
#define C_CH     32
#define H_IMG    512
#define W_IMG    512

// ---------------------------------------------------------------------------
// Kernel 1: transpose (B, C, H*W) -> (B, H*W, C) so the per-point gather of
// 32 channels becomes a contiguous 128B segment. LDS tile 32(c) x 64(hw),
// stride 65 => write phase banks hit exactly 2-way (free on wave64).
// ---------------------------------------------------------------------------
__global__ __launch_bounds__(256) void transpose_kernel(
    const float* __restrict__ in, float* __restrict__ out)
{
    const int HW = H_IMG * W_IMG;
    __shared__ float tile[C_CH * 65];

    const int tilesPerBatch = HW / 64;
    const int b   = blockIdx.x / tilesPerBatch;
    const int t   = blockIdx.x % tilesPerBatch;
    const int hw0 = t * 64;
    const int tid = threadIdx.x;

    // read phase: coalesced along HW. c_r in 0..31, u_r = (tid&7)*8
    const int c_r = tid >> 3;
    const int u_r = (tid & 7) * 8;
    const float* src = in + ((size_t)(b * C_CH + c_r) * HW + hw0 + u_r);
    float4 v0 = *(const float4*)(src);
    float4 v1 = *(const float4*)(src + 4);
    float* d = &tile[c_r * 65 + u_r];
    d[0] = v0.x; d[1] = v0.y; d[2] = v0.z; d[3] = v0.w;
    d[4] = v1.x; d[5] = v1.y; d[6] = v1.z; d[7] = v1.w;

    __syncthreads();

    // write phase: coalesced along C. u_w in 0..63, c0 in {0,8,16,24}
    const int u_w = tid >> 2;
    const int c0  = (tid & 3) * 8;
    float o[8];
#pragma unroll
    for (int k = 0; k < 8; ++k) o[k] = tile[(c0 + k) * 65 + u_w];
    float* dstg = out + ((size_t)(b * HW + hw0 + u_w) * C_CH + c0);
    *(float4*)(dstg)     = make_float4(o[0], o[1], o[2], o[3]);
    *(float4*)(dstg + 4) = make_float4(o[4], o[5], o[6], o[7]);
}

// ---------------------------------------------------------------------------
// Kernel 2: projection + bilinear gather. 64 points per 256-thread block.
// Phase A: lanes 0..63 project one point each, write record to LDS + depth.
// Phase B: lane = channel (tid&31); 4 coalesced dword gathers + lerp + store.
// TRANS=true reads the B*HW*C transposed map in d_ws; false reads raw BCHW.
// ---------------------------------------------------------------------------
template <bool TRANS>
__global__ __launch_bounds__(256) void gather_kernel(
    const int*   __restrict__ coords,
    const float* __restrict__ feat,
    const float* __restrict__ Km,
    const float* __restrict__ Pm,
    float* __restrict__ out_feat,
    float* __restrict__ out_depth,
    int N)
{
    __shared__ int   s_base[64];
    __shared__ int   s_dji[64];
    __shared__ int   s_dii[64];
    __shared__ float s_fdi[64];
    __shared__ float s_fdj[64];

    const int tid = threadIdx.x;
    const int p0  = blockIdx.x * 64;
    const int HW  = H_IMG * W_IMG;

    if (tid < 64) {
        const int p = p0 + tid;
        if (p < N) {
            int4 cc = ((const int4*)coords)[p];
            const float s = 2.0f / (float)(GRID_RES - 1);
            float wx = (float)cc.y * s - 1.0f;
            float wy = (float)cc.z * s - 1.0f;
            float wz = (float)cc.w * s - 1.0f;

            // cam = P @ [wx, wy, wz, 1]
            float cam0 = Pm[0]  * wx + Pm[1]  * wy + Pm[2]  * wz + Pm[3];
            float cam1 = Pm[4]  * wx + Pm[5]  * wy + Pm[6]  * wz + Pm[7];
            float cam2 = Pm[8]  * wx + Pm[9]  * wy + Pm[10] * wz + Pm[11];
            float cam3 = Pm[12] * wx + Pm[13] * wy + Pm[14] * wz + Pm[15];
            cam0 /= cam3; cam1 /= cam3; cam2 /= cam3;

            // img = K @ cam[:3]
            float g0 = Km[0] * cam0 + Km[1] * cam1 + Km[2] * cam2;
            float g1 = Km[3] * cam0 + Km[4] * cam1 + Km[5] * cam2;
            float g2 = Km[6] * cam0 + Km[7] * cam1 + Km[8] * cam2;
            float image_x = g0 / g2;
            float image_y = g1 / g2;

            float i0f = floorf(image_y);
            float j0f = floorf(image_x);
            float di = image_y - i0f;
            float dj = image_x - j0f;
            // clamp before int cast to avoid cvt saturation surprises
            i0f = fminf(fmaxf(i0f, -1.0e9f), 1.0e9f);
            j0f = fminf(fmaxf(j0f, -1.0e9f), 1.0e9f);
            int i0r = (int)i0f;
            int j0r = (int)j0f;
            // reference semantics: i1 = clip(raw_i0 + 1, 0, H-1)
            int i0 = min(max(i0r,     0), H_IMG - 1);
            int i1 = min(max(i0r + 1, 0), H_IMG - 1);
            int j0 = min(max(j0r,     0), W_IMG - 1);
            int j1 = min(max(j0r + 1, 0), W_IMG - 1);
            int b  = cc.x;

            int base, dji, dii;
            if (TRANS) {
                base = ((b * H_IMG + i0) * W_IMG + j0) * C_CH;
                dji  = (j1 - j0) * C_CH;
                dii  = (i1 - i0) * W_IMG * C_CH;
            } else {
                base = (b * C_CH * H_IMG + i0) * W_IMG + j0;
                dji  = (j1 - j0);
                dii  = (i1 - i0) * W_IMG;
            }
            s_base[tid] = base;
            s_dji[tid]  = dji;
            s_dii[tid]  = dii;
            s_fdi[tid]  = di;
            s_fdj[tid]  = dj;
            out_depth[p] = cam2;
        }
    }
    __syncthreads();

    const int c      = tid & 31;
    const int lpBase = tid >> 5;  // 0..7
#pragma unroll
    for (int it = 0; it < 8; ++it) {
        const int lp = it * 8 + lpBase;
        const int p  = p0 + lp;
        if (p >= N) break;  // p increases with it per-thread, so break is safe
        const int   base = s_base[lp];
        const int   dji  = s_dji[lp];
        const int   dii  = s_dii[lp];
        const float fdi  = s_fdi[lp];
        const float fdj  = s_fdj[lp];

        const float* fp = TRANS ? (feat + base + c)
                                : (feat + base + (size_t)c * HW);
        float f00 = fp[0];
        float f01 = fp[dji];
        float f10 = fp[dii];
        float f11 = fp[dii + dji];

        // i-direction first (matches reference), then j-direction
        float r0 = f00 + fdi * (f10 - f00);
        float r1 = f01 + fdi * (f11 - f01);
        out_feat[(size_t)p * C_CH + c] = r0 + fdj * (r1 - r0);
    }
}

extern "C" void kernel_launch(void* const* d_in, const int* in_sizes, int n_in,
                              void* d_out, int out_size, void* d_ws, size_t ws_size,
                              hipStream_t stream)
{
    const int*   coords = (const int*)  d_in[0];
    const float* feat   = (const float*)d_in[1];
    const float* Km     = (const float*)d_in[2];
    const float* Pm     = (const float*)d_in[3];

    const int N  = in_sizes[0] / 4;
    const int Bb = in_sizes[1] / (C_CH * H_IMG * W_IMG);
    const int HW = H_IMG * W_IMG;

    float* out_feat  = (float*)d_out;
    float* out_depth = out_feat + (size_t)N * C_CH;

    const size_t need = (size_t)in_sizes[1] * sizeof(float);
    const int nblocks = (N + 63) / 64;

    if (ws_size >= need) {
        float* tfeat = (float*)d_ws;
        transpose_kernel<<<Bb * (HW / 64), 256, 0, stream>>>(feat, tfeat);
        gather_kernel<true><<<nblocks, 256, 0, stream>>>(
            coords, tfeat, Km, Pm, out_feat, out_depth, N);
    } else {
        gather_kernel<false><<<nblocks, 256, 0, stream>>>(
            coords, feat, Km, Pm, out_feat, out_depth, N);
    }
}

// Round 2
// 477.080 us; speedup vs baseline: 1.1074x; 1.1074x over previous
//
#include <hip/hip_runtime.h>

#define GRID_RES 64
#define C_CH     32
#define H_IMG    512
#define W_IMG    512

// fp32 -> bf16 round-to-nearest-even (inputs are finite normals; NaN path unused)
__device__ __forceinline__ ushort f32_to_bf16(float f) {
    union { float f; unsigned u; } a; a.f = f;
    unsigned r = (a.u + 0x7FFFu + ((a.u >> 16) & 1u)) >> 16;
    return (ushort)r;
}
__device__ __forceinline__ float bf16lo_to_f32(unsigned u) {
    union { unsigned u; float f; } a; a.u = u << 16; return a.f;
}
__device__ __forceinline__ float bf16hi_to_f32(unsigned u) {
    union { unsigned u; float f; } a; a.u = u & 0xFFFF0000u; return a.f;
}

// ---------------------------------------------------------------------------
// Kernel 1: transpose+convert (B, C, H*W) fp32 -> (B, H*W, C) bf16.
// LDS tile 32(c) x 64(hw), stride 65 => 2-way bank aliasing only (free).
// ---------------------------------------------------------------------------
__global__ __launch_bounds__(256) void transpose_bf16_kernel(
    const float* __restrict__ in, ushort* __restrict__ out)
{
    const int HW = H_IMG * W_IMG;
    __shared__ float tile[C_CH * 65];

    const int tilesPerBatch = HW / 64;
    const int b   = blockIdx.x / tilesPerBatch;
    const int t   = blockIdx.x % tilesPerBatch;
    const int hw0 = t * 64;
    const int tid = threadIdx.x;

    // read phase: coalesced along HW. c_r in 0..31, u_r = (tid&7)*8
    const int c_r = tid >> 3;
    const int u_r = (tid & 7) * 8;
    const float* src = in + ((size_t)(b * C_CH + c_r) * HW + hw0 + u_r);
    float4 v0 = *(const float4*)(src);
    float4 v1 = *(const float4*)(src + 4);
    float* d = &tile[c_r * 65 + u_r];
    d[0] = v0.x; d[1] = v0.y; d[2] = v0.z; d[3] = v0.w;
    d[4] = v1.x; d[5] = v1.y; d[6] = v1.z; d[7] = v1.w;

    __syncthreads();

    // write phase: u_w (pixel) in 0..63, c0 in {0,8,16,24}; 16B bf16x8 store
    const int u_w = tid >> 2;
    const int c0  = (tid & 3) * 8;
    union { ushort us[8]; uint4 v; } pk;
#pragma unroll
    for (int k = 0; k < 8; ++k)
        pk.us[k] = f32_to_bf16(tile[(c0 + k) * 65 + u_w]);
    *(uint4*)(out + ((size_t)(b * HW + hw0 + u_w) * C_CH + c0)) = pk.v;
}

// ---------------------------------------------------------------------------
// Kernel 2 (bf16 path): projection + bilinear gather from (B,HW,C) bf16 map.
// 64 points / 256-thread block. Phase A: lanes 0..63 project, record to LDS,
// write depth. Phase B: lane = channel-pair (tid&15), slot = tid>>4; each
// corner load is one dword (bf16x2) -> 16 lanes cover a 64B corner segment.
// ---------------------------------------------------------------------------
__global__ __launch_bounds__(256) void gather_bf16_kernel(
    const int*    __restrict__ coords,
    const ushort* __restrict__ feat,
    const float*  __restrict__ Km,
    const float*  __restrict__ Pm,
    float* __restrict__ out_feat,
    float* __restrict__ out_depth,
    int N)
{
    __shared__ int   s_base[64];
    __shared__ int   s_dji[64];
    __shared__ int   s_dii[64];
    __shared__ float s_fdi[64];
    __shared__ float s_fdj[64];

    const int tid = threadIdx.x;
    const int p0  = blockIdx.x * 64;

    if (tid < 64) {
        const int p = p0 + tid;
        if (p < N) {
            int4 cc = ((const int4*)coords)[p];
            const float s = 2.0f / (float)(GRID_RES - 1);
            float wx = (float)cc.y * s - 1.0f;
            float wy = (float)cc.z * s - 1.0f;
            float wz = (float)cc.w * s - 1.0f;

            float cam0 = Pm[0]  * wx + Pm[1]  * wy + Pm[2]  * wz + Pm[3];
            float cam1 = Pm[4]  * wx + Pm[5]  * wy + Pm[6]  * wz + Pm[7];
            float cam2 = Pm[8]  * wx + Pm[9]  * wy + Pm[10] * wz + Pm[11];
            float cam3 = Pm[12] * wx + Pm[13] * wy + Pm[14] * wz + Pm[15];
            cam0 /= cam3; cam1 /= cam3; cam2 /= cam3;

            float g0 = Km[0] * cam0 + Km[1] * cam1 + Km[2] * cam2;
            float g1 = Km[3] * cam0 + Km[4] * cam1 + Km[5] * cam2;
            float g2 = Km[6] * cam0 + Km[7] * cam1 + Km[8] * cam2;
            float image_x = g0 / g2;
            float image_y = g1 / g2;

            float i0f = floorf(image_y);
            float j0f = floorf(image_x);
            float di = image_y - i0f;
            float dj = image_x - j0f;
            i0f = fminf(fmaxf(i0f, -1.0e9f), 1.0e9f);
            j0f = fminf(fmaxf(j0f, -1.0e9f), 1.0e9f);
            int i0r = (int)i0f;
            int j0r = (int)j0f;
            int i0 = min(max(i0r,     0), H_IMG - 1);
            int i1 = min(max(i0r + 1, 0), H_IMG - 1);
            int j0 = min(max(j0r,     0), W_IMG - 1);
            int j1 = min(max(j0r + 1, 0), W_IMG - 1);
            int b  = cc.x;

            s_base[tid] = ((b * H_IMG + i0) * W_IMG + j0) * C_CH;
            s_dji[tid]  = (j1 - j0) * C_CH;
            s_dii[tid]  = (i1 - i0) * W_IMG * C_CH;
            s_fdi[tid]  = di;
            s_fdj[tid]  = dj;
            out_depth[p] = cam2;
        }
    }
    __syncthreads();

    const int cp   = tid & 15;   // channel pair: channels 2cp, 2cp+1
    const int slot = tid >> 4;   // 0..15
#pragma unroll
    for (int it = 0; it < 4; ++it) {
        const int lp = it * 16 + slot;
        const int p  = p0 + lp;
        if (p < N) {
            const int   base = s_base[lp] + cp * 2;
            const int   dji  = s_dji[lp];
            const int   dii  = s_dii[lp];
            const float fdi  = s_fdi[lp];
            const float fdj  = s_fdj[lp];

            const unsigned u00 = *(const unsigned*)(feat + base);
            const unsigned u01 = *(const unsigned*)(feat + base + dji);
            const unsigned u10 = *(const unsigned*)(feat + base + dii);
            const unsigned u11 = *(const unsigned*)(feat + base + dii + dji);

            // low channel (2cp)
            float f00 = bf16lo_to_f32(u00), f01 = bf16lo_to_f32(u01);
            float f10 = bf16lo_to_f32(u10), f11 = bf16lo_to_f32(u11);
            float r0 = f00 + fdi * (f10 - f00);
            float r1 = f01 + fdi * (f11 - f01);
            float lo = r0 + fdj * (r1 - r0);
            // high channel (2cp+1)
            f00 = bf16hi_to_f32(u00); f01 = bf16hi_to_f32(u01);
            f10 = bf16hi_to_f32(u10); f11 = bf16hi_to_f32(u11);
            r0 = f00 + fdi * (f10 - f00);
            r1 = f01 + fdi * (f11 - f01);
            float hi = r0 + fdj * (r1 - r0);

            *(float2*)(out_feat + (size_t)p * C_CH + cp * 2) = make_float2(lo, hi);
        }
    }
}

// ---------------------------------------------------------------------------
// Fallback (no workspace): direct gather from raw BCHW fp32 (slow but correct).
// ---------------------------------------------------------------------------
__global__ __launch_bounds__(256) void gather_fp32_direct_kernel(
    const int*   __restrict__ coords,
    const float* __restrict__ feat,
    const float* __restrict__ Km,
    const float* __restrict__ Pm,
    float* __restrict__ out_feat,
    float* __restrict__ out_depth,
    int N)
{
    __shared__ int   s_base[64];
    __shared__ int   s_dji[64];
    __shared__ int   s_dii[64];
    __shared__ float s_fdi[64];
    __shared__ float s_fdj[64];

    const int tid = threadIdx.x;
    const int p0  = blockIdx.x * 64;
    const int HW  = H_IMG * W_IMG;

    if (tid < 64) {
        const int p = p0 + tid;
        if (p < N) {
            int4 cc = ((const int4*)coords)[p];
            const float s = 2.0f / (float)(GRID_RES - 1);
            float wx = (float)cc.y * s - 1.0f;
            float wy = (float)cc.z * s - 1.0f;
            float wz = (float)cc.w * s - 1.0f;
            float cam0 = Pm[0]  * wx + Pm[1]  * wy + Pm[2]  * wz + Pm[3];
            float cam1 = Pm[4]  * wx + Pm[5]  * wy + Pm[6]  * wz + Pm[7];
            float cam2 = Pm[8]  * wx + Pm[9]  * wy + Pm[10] * wz + Pm[11];
            float cam3 = Pm[12] * wx + Pm[13] * wy + Pm[14] * wz + Pm[15];
            cam0 /= cam3; cam1 /= cam3; cam2 /= cam3;
            float g0 = Km[0] * cam0 + Km[1] * cam1 + Km[2] * cam2;
            float g1 = Km[3] * cam0 + Km[4] * cam1 + Km[5] * cam2;
            float g2 = Km[6] * cam0 + Km[7] * cam1 + Km[8] * cam2;
            float image_x = g0 / g2;
            float image_y = g1 / g2;
            float i0f = floorf(image_y);
            float j0f = floorf(image_x);
            float di = image_y - i0f;
            float dj = image_x - j0f;
            i0f = fminf(fmaxf(i0f, -1.0e9f), 1.0e9f);
            j0f = fminf(fmaxf(j0f, -1.0e9f), 1.0e9f);
            int i0r = (int)i0f;
            int j0r = (int)j0f;
            int i0 = min(max(i0r,     0), H_IMG - 1);
            int i1 = min(max(i0r + 1, 0), H_IMG - 1);
            int j0 = min(max(j0r,     0), W_IMG - 1);
            int j1 = min(max(j0r + 1, 0), W_IMG - 1);
            int b  = cc.x;
            s_base[tid] = (b * C_CH * H_IMG + i0) * W_IMG + j0;
            s_dji[tid]  = (j1 - j0);
            s_dii[tid]  = (i1 - i0) * W_IMG;
            s_fdi[tid]  = di;
            s_fdj[tid]  = dj;
            out_depth[p] = cam2;
        }
    }
    __syncthreads();

    const int c      = tid & 31;
    const int lpBase = tid >> 5;
#pragma unroll
    for (int it = 0; it < 8; ++it) {
        const int lp = it * 8 + lpBase;
        const int p  = p0 + lp;
        if (p < N) {
            const int   base = s_base[lp];
            const int   dji  = s_dji[lp];
            const int   dii  = s_dii[lp];
            const float fdi  = s_fdi[lp];
            const float fdj  = s_fdj[lp];
            const float* fp = feat + base + (size_t)c * HW;
            float f00 = fp[0];
            float f01 = fp[dji];
            float f10 = fp[dii];
            float f11 = fp[dii + dji];
            float r0 = f00 + fdi * (f10 - f00);
            float r1 = f01 + fdi * (f11 - f01);
            out_feat[(size_t)p * C_CH + c] = r0 + fdj * (r1 - r0);
        }
    }
}

extern "C" void kernel_launch(void* const* d_in, const int* in_sizes, int n_in,
                              void* d_out, int out_size, void* d_ws, size_t ws_size,
                              hipStream_t stream)
{
    const int*   coords = (const int*)  d_in[0];
    const float* feat   = (const float*)d_in[1];
    const float* Km     = (const float*)d_in[2];
    const float* Pm     = (const float*)d_in[3];

    const int N  = in_sizes[0] / 4;
    const int Bb = in_sizes[1] / (C_CH * H_IMG * W_IMG);
    const int HW = H_IMG * W_IMG;

    float* out_feat  = (float*)d_out;
    float* out_depth = out_feat + (size_t)N * C_CH;

    const size_t need = (size_t)in_sizes[1] * sizeof(ushort);  // bf16 map
    const int nblocks = (N + 63) / 64;

    if (ws_size >= need) {
        ushort* tfeat = (ushort*)d_ws;
        transpose_bf16_kernel<<<Bb * (HW / 64), 256, 0, stream>>>(feat, tfeat);
        gather_bf16_kernel<<<nblocks, 256, 0, stream>>>(
            coords, tfeat, Km, Pm, out_feat, out_depth, N);
    } else {
        gather_fp32_direct_kernel<<<nblocks, 256, 0, stream>>>(
            coords, feat, Km, Pm, out_feat, out_depth, N);
    }
}